// Round 15
// baseline (157.899 us; speedup 1.0000x reference)
//
#include <hip/hip_runtime.h>

#define NN 1000
#define HEADS_ 4
#define DM 128
#define EE 64000
#define NTOT 4000
#define ETOT 68000
#define CAP 48     // bucket holds ALL edges per dst: deg ~ Poisson(16)+1, P(>=48) ~ 1e-11
#define EB 34      // edge-builder blocks appended to the h-GEMM dispatch
#define TB 10      // transpose blocks (8 for inw, 2 for outw)

// ---------------------------------------------------------------------------
// k1 GEMM body: 64x64 tile, K=64, swizzle g = q ^ ((r>>2)&15), acc[4][4] --
// proven spill-free (R2/R5/R9, 60-84 VGPR).  Fused GAT score epilogue.
// ---------------------------------------------------------------------------
__device__ void gemm64_k1(float* As, float* Bs, int mi, int ni,
                          const float* __restrict__ x, const float* __restrict__ W,
                          float* __restrict__ hbuf, const float* __restrict__ att,
                          float* __restrict__ ssrc, float* __restrict__ sdst) {
  int tid = threadIdx.x;
  int m0 = mi * 64, n0 = ni * 64;
  int tx = tid & 15, ty = tid >> 4;
  const float4* A4 = (const float4*)x;   // [16000][16]
  const float4* W4 = (const float4*)W;   // [128][16]
  float acc[4][4] = {};

  __syncthreads();
  {
    int q = tid & 15, r0 = tid >> 4;
#pragma unroll
    for (int p = 0; p < 4; ++p) {  // A: 64 rows
      int r = r0 + p * 16;
      float4 v = A4[(size_t)(m0 + r) * 16 + q];
      *(float4*)&As[r * 64 + ((q ^ ((r >> 2) & 15)) << 2)] = v;
    }
#pragma unroll
    for (int p = 0; p < 4; ++p) {  // B: 64 rows
      int r = r0 + p * 16;
      float4 v = W4[(size_t)(n0 + r) * 16 + q];
      *(float4*)&Bs[r * 64 + ((q ^ ((r >> 2) & 15)) << 2)] = v;
    }
  }
  __syncthreads();
#pragma unroll 4
  for (int q = 0; q < 16; ++q) {
    float4 a[4], b[4];
    int sa = (q ^ ty) << 2;
    int sb = (q ^ tx) << 2;
#pragma unroll
    for (int i = 0; i < 4; ++i)
      a[i] = *(const float4*)&As[(ty * 4 + i) * 64 + sa];
#pragma unroll
    for (int j = 0; j < 4; ++j)
      b[j] = *(const float4*)&Bs[(tx * 4 + j) * 64 + sb];
#pragma unroll
    for (int i = 0; i < 4; ++i)
#pragma unroll
      for (int j = 0; j < 4; ++j)
        acc[i][j] += a[i].x * b[j].x + a[i].y * b[j].y
                   + a[i].z * b[j].z + a[i].w * b[j].w;
  }

  int nc = n0 + tx * 4;
#pragma unroll
  for (int i = 0; i < 4; ++i) {
    int m = m0 + ty * 4 + i;
    *(float4*)&hbuf[(size_t)m * DM + nc] =
        make_float4(acc[i][0], acc[i][1], acc[i][2], acc[i][3]);
  }

  if (m0 < NN) {  // fused GAT score epilogue (rows < 1000 only)
    int hsel = tx >> 3;
    int h = ni * 2 + hsel;
    int kb = (tx & 7) * 4;
    float a0[4], a1[4];
#pragma unroll
    for (int j = 0; j < 4; ++j) {
      a0[j] = att[h * 64 + kb + j];
      a1[j] = att[h * 64 + 32 + kb + j];
    }
#pragma unroll
    for (int i = 0; i < 4; ++i) {
      int m = m0 + ty * 4 + i;
      float p0 = 0.f, p1 = 0.f;
#pragma unroll
      for (int j = 0; j < 4; ++j) {
        float g = acc[i][j];
        float lr = g > 0.f ? g : 0.2f * g;
        p0 += a0[j] * lr;
        p1 += a1[j] * lr;
      }
      p0 += __shfl_xor(p0, 1, 16); p1 += __shfl_xor(p1, 1, 16);
      p0 += __shfl_xor(p0, 2, 16); p1 += __shfl_xor(p1, 2, 16);
      p0 += __shfl_xor(p0, 4, 16); p1 += __shfl_xor(p1, 4, 16);
      if ((tx & 7) == 0 && m < NN) {
        ssrc[m * HEADS_ + h] = p0;
        sdst[m * HEADS_ + h] = p1;
      }
    }
  }
}

// -------- K1: blocks 0..499 = h-GEMM + score | 500..533 = bucket build
//              534..543 = weight transposes (inwT[k][col], outwT[k][col])
__global__ __launch_bounds__(256) void k1_kernel(const float* __restrict__ x,
                                                 const float* __restrict__ W,
                                                 const float* __restrict__ att,
                                                 float* __restrict__ hbuf,
                                                 float* __restrict__ ssrc,
                                                 float* __restrict__ sdst,
                                                 const int* __restrict__ ei,
                                                 int* __restrict__ cnt,
                                                 int* __restrict__ elist,
                                                 const float* __restrict__ inw,
                                                 const float* __restrict__ outw,
                                                 float* __restrict__ inwT,
                                                 float* __restrict__ outwT) {
  __shared__ float smem[8192];
  int bid = blockIdx.x;
  if (bid < 500) {
    gemm64_k1(smem, smem + 4096, bid >> 1, bid & 1, x, W, hbuf, att, ssrc, sdst);
  } else if (bid < 500 + EB) {
    for (int e = (bid - 500) * 256 + threadIdx.x; e < ETOT; e += EB * 256) {
      int s, d;
      if (e < EE) { s = ei[e]; d = ei[EE + e]; }
      else { s = d = e - EE; }  // self loops
      int pos = atomicAdd(&cnt[d], 1);
      if (pos < CAP) elist[d * CAP + pos] = s;
    }
  } else {
    int tb = bid - (500 + EB);
    if (tb < 8) {        // inw [384][128] -> inwT [128][384]
      for (int g = tb * 6144 + threadIdx.x; g < (tb + 1) * 6144; g += 256) {
        int col = g >> 7, k = g & 127;          // coalesced read (k fast)
        inwT[k * 384 + col] = inw[(size_t)col * 128 + k];
      }
    } else {             // outw [128][128] -> outwT [128][128]
      int ob = tb - 8;
      for (int g = ob * 8192 + threadIdx.x; g < (ob + 1) * 8192; g += 256) {
        int col = g >> 7, k = g & 127;
        outwT[k * 128 + col] = outw[(size_t)col * 128 + k];
      }
    }
  }
}

// ---------------------------------------------------------------------------
// K2 (mega2 v6): R14's global-B structure (passed, 60.5us, VGPR 60, 0
// conflicts) at DOUBLE the wave density.  R14's invariant: 32 threads/node
// -> 2000 waves -> ~2/SIMD no matter the grid.  Here: 64 threads/node
// (2 cols/thread, acc[3][4][2]), 4 nodes/block, 256 threads, 1000 blocks ->
// 4000 waves -> ~4/SIMD.  B-operands stay on the global-coalesced inwT/outwT
// path (no LDS staging -> R12's conflict/amplification mechanism absent).
// Head-reduce = shfl_xor 1/2/4/8 over the 16-lane head group (lane = tx in
// [16h,16h+16) -> in-head, in-wave; wave = node ty).  A2 = R12's verified
// 2-head-slice gather.  LDS 21 KB; kg-loop bound opaque (anti-hoist, R13).
// ---------------------------------------------------------------------------
__global__ __launch_bounds__(256) void mega2_kernel(const int* __restrict__ cnt,
                                                    const int* __restrict__ elist,
                                                    const float* __restrict__ ssrc,
                                                    const float* __restrict__ sdst,
                                                    const float* __restrict__ hbuf,
                                                    const float* __restrict__ inwT,
                                                    const float* __restrict__ inb,
                                                    const float* __restrict__ outwT,
                                                    const float* __restrict__ outb,
                                                    const float* __restrict__ bias,
                                                    float* __restrict__ out) {
  __shared__ float smem[3136];           // 12,544 B
  float* As    = smem;                   // [16][132]
  float* exsF  = smem + 2112;            // [4][48][4]
  int*   srcsI = (int*)(smem + 2112 + 768);  // [4][48]
  float* aoS   = smem;                   // [16][132] (overlay on As after B)

  int tid = threadIdx.x;
  int g0n = blockIdx.x * 4;              // first node of tile
  int kgN = (int)(blockDim.x >> 3);      // == 32, opaque to the compiler

  // ---- phase A1: stage edges + exp(score per head): 64 threads/node ----
  {
    int ln = tid >> 6, t64 = tid & 63;
    int d = g0n + ln;
    int m = cnt[d]; if (m > CAP) m = CAP;
    float sd = (d < NN) ? sdst[d * HEADS_ + (t64 & 3)] : 0.f;  // uniform/ln
    for (int base = 0; base < m; base += 16) {
      int i = base + (t64 >> 2);
      if (i < m) {
        int s = elist[d * CAP + i];
        if ((t64 & 3) == 0) srcsI[ln * CAP + i] = s;
        float ss = (s < NN) ? ssrc[s * HEADS_ + (t64 & 3)] : 0.f;
        exsF[ln * 192 + i * 4 + (t64 & 3)] = __expf(ss + sd);  // shift-invariant
      }
    }
  }
  __syncthreads();

  // ---- phase A2: gather into As; 16 thr/row, 2 head-slices (R12-verified) --
  {
    int r = tid >> 4, f = tid & 15;      // row in [0,16), f4-group in [0,16)
    int ln = r >> 2, v = r & 3;
    int d = g0n + ln, b = d / NN;
    int m = cnt[d]; if (m > CAP) m = CAP;
    int h_lo = f >> 3, h_hi = 2 + (f >> 3);
    const float* hbase = hbuf + ((size_t)(b * 4 + v) * NN) * DM + f * 4;
    float4 alo = make_float4(0.f, 0.f, 0.f, 0.f), ahi = alo;
    float dlo = 1e-16f, dhi = 1e-16f;
    int i = 0;
    for (; i + 4 <= m; i += 4) {
      float exl[4], exh[4]; unsigned sl[4]; const float* hrow[4];
#pragma unroll
      for (int u = 0; u < 4; ++u) {
        exl[u] = exsF[ln * 192 + (i + u) * 4 + h_lo];
        exh[u] = exsF[ln * 192 + (i + u) * 4 + h_hi];
        sl[u] = (unsigned)(srcsI[ln * CAP + i + u] - b * NN);
        unsigned sc = sl[u] < NN ? sl[u] : 0u;   // clamped always-valid addr
        hrow[u] = hbase + (size_t)sc * DM;
      }
      float4 hl[4], hh[4];
#pragma unroll
      for (int u = 0; u < 4; ++u) {              // 8 loads in flight
        hl[u] = *(const float4*)(hrow[u]);
        hh[u] = *(const float4*)(hrow[u] + 64);
      }
#pragma unroll
      for (int u = 0; u < 4; ++u) {
        dlo += exl[u]; dhi += exh[u];
        float wl = sl[u] < NN ? exl[u] : 0.f, wh = sl[u] < NN ? exh[u] : 0.f;
        alo.x += wl * hl[u].x; alo.y += wl * hl[u].y;
        alo.z += wl * hl[u].z; alo.w += wl * hl[u].w;
        ahi.x += wh * hh[u].x; ahi.y += wh * hh[u].y;
        ahi.z += wh * hh[u].z; ahi.w += wh * hh[u].w;
      }
    }
    for (; i < m; ++i) {
      float exl = exsF[ln * 192 + i * 4 + h_lo];
      float exh = exsF[ln * 192 + i * 4 + h_hi];
      unsigned sl = (unsigned)(srcsI[ln * CAP + i] - b * NN);
      unsigned sc = sl < NN ? sl : 0u;
      const float* hrow = hbase + (size_t)sc * DM;
      float4 hl = *(const float4*)(hrow);
      float4 hh = *(const float4*)(hrow + 64);
      dlo += exl; dhi += exh;
      float wl = sl < NN ? exl : 0.f, wh = sl < NN ? exh : 0.f;
      alo.x += wl * hl.x; alo.y += wl * hl.y; alo.z += wl * hl.z; alo.w += wl * hl.w;
      ahi.x += wh * hh.x; ahi.y += wh * hh.y; ahi.z += wh * hh.z; ahi.w += wh * hh.w;
    }
    float il = 1.f / dlo, ih = 1.f / dhi;
    *(float4*)&As[r * 132 +      f * 4] = make_float4(alo.x * il, alo.y * il, alo.z * il, alo.w * il);
    *(float4*)&As[r * 132 + 64 + f * 4] = make_float4(ahi.x * ih, ahi.y * ih, ahi.z * ih, ahi.w * ih);
  }
  __syncthreads();

  // ---- phase B: qkv via outer-product; A broadcast from LDS, B from
  //      coalesced global inwT[k][col] (float2/lane); NO staging/barriers ----
  int tx = tid & 63, ty = tid >> 6;      // cols {p*128 + tx*2, +1}, node ty
  float acc[3][4][2] = {};
  {
    const float2* BT = (const float2*)inwT;   // [128][192 f2]
    for (int kg = 0; kg < kgN; ++kg) {        // 32 iters, rolled (opaque bound)
      float4 a4[4];
#pragma unroll
      for (int i = 0; i < 4; ++i)             // wave-uniform rows -> broadcast
        a4[i] = *(const float4*)&As[(ty * 4 + i) * 132 + kg * 4];
      float2 bb[12];
#pragma unroll
      for (int kk = 0; kk < 4; ++kk)
#pragma unroll
        for (int p = 0; p < 3; ++p)           // coalesced: lane tx consecutive
          bb[kk * 3 + p] = BT[(size_t)(kg * 4 + kk) * 192 + p * 64 + tx];
#pragma unroll
      for (int kk = 0; kk < 4; ++kk) {
        float av[4];
#pragma unroll
        for (int i = 0; i < 4; ++i)
          av[i] = kk == 0 ? a4[i].x : kk == 1 ? a4[i].y : kk == 2 ? a4[i].z : a4[i].w;
#pragma unroll
        for (int p = 0; p < 3; ++p) {
          float2 b = bb[kk * 3 + p];
#pragma unroll
          for (int i = 0; i < 4; ++i) {
            acc[p][i][0] += av[i] * b.x;
            acc[p][i][1] += av[i] * b.y;
          }
        }
      }
    }
  }

  // ---- phase C: +inb, then attention entirely in registers ----
  // acc[p][v][j] = {q,k,v}[node ty][view v][col tx*2+j]; head = tx>>4.
#pragma unroll
  for (int ni = 0; ni < 3; ++ni) {
    float b0 = inb[ni * 128 + tx * 2], b1 = inb[ni * 128 + tx * 2 + 1];
#pragma unroll
    for (int i = 0; i < 4; ++i) { acc[ni][i][0] += b0; acc[ni][i][1] += b1; }
  }
  float S[4][4];
#pragma unroll
  for (int vq = 0; vq < 4; ++vq)
#pragma unroll
    for (int vk = 0; vk < 4; ++vk)
      S[vq][vk] = acc[0][vq][0] * acc[1][vk][0] + acc[0][vq][1] * acc[1][vk][1];
  // reduce over the head's 16 tx-lanes (xor 1/2/4/8 flips tx bits 0-3 only)
#pragma unroll
  for (int vq = 0; vq < 4; ++vq)
#pragma unroll
    for (int vk = 0; vk < 4; ++vk) {
      float s = S[vq][vk];
      s += __shfl_xor(s, 1);
      s += __shfl_xor(s, 2);
      s += __shfl_xor(s, 4);
      s += __shfl_xor(s, 8);
      S[vq][vk] = s * 0.17677669529663687f;  // 1/sqrt(32)
    }
#pragma unroll
  for (int vq = 0; vq < 4; ++vq) {  // softmax over vk (redundant x16)
    float mx = fmaxf(fmaxf(S[vq][0], S[vq][1]), fmaxf(S[vq][2], S[vq][3]));
    float e0 = __expf(S[vq][0] - mx), e1 = __expf(S[vq][1] - mx);
    float e2 = __expf(S[vq][2] - mx), e3 = __expf(S[vq][3] - mx);
    float inv = 1.f / (e0 + e1 + e2 + e3);
    S[vq][0] = e0 * inv; S[vq][1] = e1 * inv; S[vq][2] = e2 * inv; S[vq][3] = e3 * inv;
  }
  float ao0[4], ao1[4];
#pragma unroll
  for (int vq = 0; vq < 4; ++vq) {
    ao0[vq] = S[vq][0] * acc[2][0][0] + S[vq][1] * acc[2][1][0]
            + S[vq][2] * acc[2][2][0] + S[vq][3] * acc[2][3][0];
    ao1[vq] = S[vq][0] * acc[2][0][1] + S[vq][1] * acc[2][1][1]
            + S[vq][2] * acc[2][2][1] + S[vq][3] * acc[2][3][1];
  }
  __syncthreads();  // all As reads (phase B) complete before aoS overlay
#pragma unroll
  for (int vq = 0; vq < 4; ++vq)         // plain padded rows; k contiguous
    *(float2*)&aoS[(ty * 4 + vq) * 132 + tx * 2] = make_float2(ao0[vq], ao1[vq]);
  __syncthreads();

  // ---- phase D: out_proj via outer-product; aoS broadcast + outwT global --
  float oc[4][2] = {};
  {
    const float2* OT = (const float2*)outwT;  // [128][64 f2]
    for (int kg = 0; kg < kgN; ++kg) {        // 32 iters, rolled
      float4 a4[4];
#pragma unroll
      for (int i = 0; i < 4; ++i)
        a4[i] = *(const float4*)&aoS[(ty * 4 + i) * 132 + kg * 4];
      float2 bb[4];
#pragma unroll
      for (int kk = 0; kk < 4; ++kk)          // coalesced
        bb[kk] = OT[(size_t)(kg * 4 + kk) * 64 + tx];
#pragma unroll
      for (int kk = 0; kk < 4; ++kk) {
        float av[4];
#pragma unroll
        for (int i = 0; i < 4; ++i)
          av[i] = kk == 0 ? a4[i].x : kk == 1 ? a4[i].y : kk == 2 ? a4[i].z : a4[i].w;
        float2 b = bb[kk];
#pragma unroll
        for (int i = 0; i < 4; ++i) {
          oc[i][0] += av[i] * b.x;
          oc[i][1] += av[i] * b.y;
        }
      }
    }
  }

  {  // epilogue: +outb +bias, remap row (node,v) -> (b*4+v)*NN + n
    int nc = tx * 2;
    float o0 = outb[nc] + bias[nc], o1 = outb[nc + 1] + bias[nc + 1];
#pragma unroll
    for (int i = 0; i < 4; ++i) {
      int node = g0n + ty, vv = i;       // rows ty*4+i => node ty, view i
      int bg = node / NN, n = node - bg * NN;
      int om = (bg * 4 + vv) * NN + n;
      *(float2*)&out[(size_t)om * DM + nc] = make_float2(oc[i][0] + o0, oc[i][1] + o1);
    }
  }
}

extern "C" void kernel_launch(void* const* d_in, const int* in_sizes, int n_in,
                              void* d_out, int out_size, void* d_ws, size_t ws_size,
                              hipStream_t stream) {
  const float* x    = (const float*)d_in[0];
  const float* W    = (const float*)d_in[1];
  const float* att  = (const float*)d_in[2];
  const float* inw  = (const float*)d_in[3];
  const float* inb  = (const float*)d_in[4];
  const float* outw = (const float*)d_in[5];
  const float* outb = (const float*)d_in[6];
  const float* bias = (const float*)d_in[7];
  const int*   ei   = (const int*)d_in[8];
  float* out = (float*)d_out;

  float* ws = (float*)d_ws;
  float* hbuf  = ws;                       // 2,048,000  (b,v,n)-major h
  float* ssrc  = ws + 12500000;            // 16,000 (rows>=1000 never read)
  float* sdst  = ssrc + 16000;             // 16,000
  int*   cnt   = (int*)(sdst + 16000);     //  4,000
  int*   elist = cnt + 4000;               // 192,000 (4000 x CAP)
  float* inwT  = ws + 12800000;            // 49,152  [128][384]
  float* outwT = ws + 12900000;            // 16,384  [128][128]

  // zero cnt only (score reads are predicated)
  hipMemsetAsync(cnt, 0, 4000 * sizeof(int), stream);

  k1_kernel<<<500 + EB + TB, 256, 0, stream>>>(x, W, att, hbuf, ssrc, sdst,
                                               ei, cnt, elist, inw, outw,
                                               inwT, outwT);
  mega2_kernel<<<NTOT / 4, 256, 0, stream>>>(cnt, elist, ssrc, sdst, hbuf,
                                             inwT, inb, outwT, outb, bias, out);
}

// Round 16
// 154.831 us; speedup vs baseline: 1.0198x; 1.0198x over previous
//
#include <hip/hip_runtime.h>

#define NN 1000
#define HEADS_ 4
#define DM 128
#define EE 64000
#define NTOT 4000
#define ETOT 68000
#define CAP 48     // bucket holds ALL edges per dst: deg ~ Poisson(16)+1, P(>=48) ~ 1e-11
#define EB 34      // edge-builder blocks appended to the h-GEMM dispatch
#define TB 10      // transpose blocks (8 for inw, 2 for outw)

// ---------------------------------------------------------------------------
// k1 GEMM body: 64x64 tile, K=64, swizzle g = q ^ ((r>>2)&15), acc[4][4] --
// proven spill-free (R2/R5/R9, 60-84 VGPR).  Fused GAT score epilogue.
// ---------------------------------------------------------------------------
__device__ void gemm64_k1(float* As, float* Bs, int mi, int ni,
                          const float* __restrict__ x, const float* __restrict__ W,
                          float* __restrict__ hbuf, const float* __restrict__ att,
                          float* __restrict__ ssrc, float* __restrict__ sdst) {
  int tid = threadIdx.x;
  int m0 = mi * 64, n0 = ni * 64;
  int tx = tid & 15, ty = tid >> 4;
  const float4* A4 = (const float4*)x;   // [16000][16]
  const float4* W4 = (const float4*)W;   // [128][16]
  float acc[4][4] = {};

  __syncthreads();
  {
    int q = tid & 15, r0 = tid >> 4;
#pragma unroll
    for (int p = 0; p < 4; ++p) {  // A: 64 rows
      int r = r0 + p * 16;
      float4 v = A4[(size_t)(m0 + r) * 16 + q];
      *(float4*)&As[r * 64 + ((q ^ ((r >> 2) & 15)) << 2)] = v;
    }
#pragma unroll
    for (int p = 0; p < 4; ++p) {  // B: 64 rows
      int r = r0 + p * 16;
      float4 v = W4[(size_t)(n0 + r) * 16 + q];
      *(float4*)&Bs[r * 64 + ((q ^ ((r >> 2) & 15)) << 2)] = v;
    }
  }
  __syncthreads();
#pragma unroll 4
  for (int q = 0; q < 16; ++q) {
    float4 a[4], b[4];
    int sa = (q ^ ty) << 2;
    int sb = (q ^ tx) << 2;
#pragma unroll
    for (int i = 0; i < 4; ++i)
      a[i] = *(const float4*)&As[(ty * 4 + i) * 64 + sa];
#pragma unroll
    for (int j = 0; j < 4; ++j)
      b[j] = *(const float4*)&Bs[(tx * 4 + j) * 64 + sb];
#pragma unroll
    for (int i = 0; i < 4; ++i)
#pragma unroll
      for (int j = 0; j < 4; ++j)
        acc[i][j] += a[i].x * b[j].x + a[i].y * b[j].y
                   + a[i].z * b[j].z + a[i].w * b[j].w;
  }

  int nc = n0 + tx * 4;
#pragma unroll
  for (int i = 0; i < 4; ++i) {
    int m = m0 + ty * 4 + i;
    *(float4*)&hbuf[(size_t)m * DM + nc] =
        make_float4(acc[i][0], acc[i][1], acc[i][2], acc[i][3]);
  }

  if (m0 < NN) {  // fused GAT score epilogue (rows < 1000 only)
    int hsel = tx >> 3;
    int h = ni * 2 + hsel;
    int kb = (tx & 7) * 4;
    float a0[4], a1[4];
#pragma unroll
    for (int j = 0; j < 4; ++j) {
      a0[j] = att[h * 64 + kb + j];
      a1[j] = att[h * 64 + 32 + kb + j];
    }
#pragma unroll
    for (int i = 0; i < 4; ++i) {
      int m = m0 + ty * 4 + i;
      float p0 = 0.f, p1 = 0.f;
#pragma unroll
      for (int j = 0; j < 4; ++j) {
        float g = acc[i][j];
        float lr = g > 0.f ? g : 0.2f * g;
        p0 += a0[j] * lr;
        p1 += a1[j] * lr;
      }
      p0 += __shfl_xor(p0, 1, 16); p1 += __shfl_xor(p1, 1, 16);
      p0 += __shfl_xor(p0, 2, 16); p1 += __shfl_xor(p1, 2, 16);
      p0 += __shfl_xor(p0, 4, 16); p1 += __shfl_xor(p1, 4, 16);
      if ((tx & 7) == 0 && m < NN) {
        ssrc[m * HEADS_ + h] = p0;
        sdst[m * HEADS_ + h] = p1;
      }
    }
  }
}

// -------- K1: blocks 0..499 = h-GEMM + score | 500..533 = bucket build
//              534..543 = weight transposes (inwT[k][col], outwT[k][col])
__global__ __launch_bounds__(256) void k1_kernel(const float* __restrict__ x,
                                                 const float* __restrict__ W,
                                                 const float* __restrict__ att,
                                                 float* __restrict__ hbuf,
                                                 float* __restrict__ ssrc,
                                                 float* __restrict__ sdst,
                                                 const int* __restrict__ ei,
                                                 int* __restrict__ cnt,
                                                 int* __restrict__ elist,
                                                 const float* __restrict__ inw,
                                                 const float* __restrict__ outw,
                                                 float* __restrict__ inwT,
                                                 float* __restrict__ outwT) {
  __shared__ float smem[8192];
  int bid = blockIdx.x;
  if (bid < 500) {
    gemm64_k1(smem, smem + 4096, bid >> 1, bid & 1, x, W, hbuf, att, ssrc, sdst);
  } else if (bid < 500 + EB) {
    for (int e = (bid - 500) * 256 + threadIdx.x; e < ETOT; e += EB * 256) {
      int s, d;
      if (e < EE) { s = ei[e]; d = ei[EE + e]; }
      else { s = d = e - EE; }  // self loops
      int pos = atomicAdd(&cnt[d], 1);
      if (pos < CAP) elist[d * CAP + pos] = s;
    }
  } else {
    int tb = bid - (500 + EB);
    if (tb < 8) {        // inw [384][128] -> inwT [128][384]
      for (int g = tb * 6144 + threadIdx.x; g < (tb + 1) * 6144; g += 256) {
        int col = g >> 7, k = g & 127;          // coalesced read (k fast)
        inwT[k * 384 + col] = inw[(size_t)col * 128 + k];
      }
    } else {             // outw [128][128] -> outwT [128][128]
      int ob = tb - 8;
      for (int g = ob * 8192 + threadIdx.x; g < (ob + 1) * 8192; g += 256) {
        int col = g >> 7, k = g & 127;
        outwT[k * 128 + col] = outw[(size_t)col * 128 + k];
      }
    }
  }
}

// ---------------------------------------------------------------------------
// K2 (mega2 v7): clean 4-waves/SIMD test.  R14's proven global-B float4 path
// (passed, 60.5us, VGPR 48-60, 0 conflicts) with SPLIT-K across lane halves:
// 512 threads, 8 nodes/block, grid 500 -> 4000 waves ~ 4/SIMD (2x R14).
// Thread = (node ln = tid>>6, k-half kh = (tid>>5)&1, cols tx*4, tx in
// [0,32)).  Each thread runs HALF the kg-chain (16 iters) with the SAME
// float4 loads -> total VMEM instr count == R14 (R15's f2 doubling undone),
// per-thread serial chain halved.  Partials reduced by one shfl_xor(acc,32)
// (both halves then hold full sums; redundant-consistent attention, as
// R14's redundant softmax); kh==0 lanes write aoS / out.
// A1/A2 = R12/R15-verified 64-thr/node + 2-head-slice gather.  LDS 26 KB.
// ---------------------------------------------------------------------------
__global__ __launch_bounds__(512) void mega2_kernel(const int* __restrict__ cnt,
                                                    const int* __restrict__ elist,
                                                    const float* __restrict__ ssrc,
                                                    const float* __restrict__ sdst,
                                                    const float* __restrict__ hbuf,
                                                    const float* __restrict__ inwT,
                                                    const float* __restrict__ inb,
                                                    const float* __restrict__ outwT,
                                                    const float* __restrict__ outb,
                                                    const float* __restrict__ bias,
                                                    float* __restrict__ out) {
  __shared__ float smem[6528];           // 26,112 B
  float* As    = smem;                   // [32][132]
  float* exsF  = smem + 4224;            // [8][48][4]
  int*   srcsI = (int*)(smem + 4224 + 1536);  // [8][48]
  float* aoS   = smem;                   // [32][132] (overlay on As after B)

  int tid = threadIdx.x;
  int g0n = blockIdx.x * 8;              // first node of tile
  int kgH = (int)(blockDim.x >> 5);      // == 16, opaque to the compiler

  // ---- phase A1: stage edges + exp(score per head): 64 threads/node ----
  {
    int ln = tid >> 6, t64 = tid & 63;
    int d = g0n + ln;
    int m = cnt[d]; if (m > CAP) m = CAP;
    float sd = (d < NN) ? sdst[d * HEADS_ + (t64 & 3)] : 0.f;  // uniform/ln
    for (int base = 0; base < m; base += 16) {
      int i = base + (t64 >> 2);
      if (i < m) {
        int s = elist[d * CAP + i];
        if ((t64 & 3) == 0) srcsI[ln * CAP + i] = s;
        float ss = (s < NN) ? ssrc[s * HEADS_ + (t64 & 3)] : 0.f;
        exsF[ln * 192 + i * 4 + (t64 & 3)] = __expf(ss + sd);  // shift-invariant
      }
    }
  }
  __syncthreads();

  // ---- phase A2: gather into As; 32 rows, 16 thr/row, 2 head-slices ----
  {
    int r = tid >> 4, f = tid & 15;      // row in [0,32), f4-group in [0,16)
    int ln = r >> 2, v = r & 3;
    int d = g0n + ln, b = d / NN;
    int m = cnt[d]; if (m > CAP) m = CAP;
    int h_lo = f >> 3, h_hi = 2 + (f >> 3);
    const float* hbase = hbuf + ((size_t)(b * 4 + v) * NN) * DM + f * 4;
    float4 alo = make_float4(0.f, 0.f, 0.f, 0.f), ahi = alo;
    float dlo = 1e-16f, dhi = 1e-16f;
    int i = 0;
    for (; i + 4 <= m; i += 4) {
      float exl[4], exh[4]; unsigned sl[4]; const float* hrow[4];
#pragma unroll
      for (int u = 0; u < 4; ++u) {
        exl[u] = exsF[ln * 192 + (i + u) * 4 + h_lo];
        exh[u] = exsF[ln * 192 + (i + u) * 4 + h_hi];
        sl[u] = (unsigned)(srcsI[ln * CAP + i + u] - b * NN);
        unsigned sc = sl[u] < NN ? sl[u] : 0u;   // clamped always-valid addr
        hrow[u] = hbase + (size_t)sc * DM;
      }
      float4 hl[4], hh[4];
#pragma unroll
      for (int u = 0; u < 4; ++u) {              // 8 loads in flight
        hl[u] = *(const float4*)(hrow[u]);
        hh[u] = *(const float4*)(hrow[u] + 64);
      }
#pragma unroll
      for (int u = 0; u < 4; ++u) {
        dlo += exl[u]; dhi += exh[u];
        float wl = sl[u] < NN ? exl[u] : 0.f, wh = sl[u] < NN ? exh[u] : 0.f;
        alo.x += wl * hl[u].x; alo.y += wl * hl[u].y;
        alo.z += wl * hl[u].z; alo.w += wl * hl[u].w;
        ahi.x += wh * hh[u].x; ahi.y += wh * hh[u].y;
        ahi.z += wh * hh[u].z; ahi.w += wh * hh[u].w;
      }
    }
    for (; i < m; ++i) {
      float exl = exsF[ln * 192 + i * 4 + h_lo];
      float exh = exsF[ln * 192 + i * 4 + h_hi];
      unsigned sl = (unsigned)(srcsI[ln * CAP + i] - b * NN);
      unsigned sc = sl < NN ? sl : 0u;
      const float* hrow = hbase + (size_t)sc * DM;
      float4 hl = *(const float4*)(hrow);
      float4 hh = *(const float4*)(hrow + 64);
      dlo += exl; dhi += exh;
      float wl = sl < NN ? exl : 0.f, wh = sl < NN ? exh : 0.f;
      alo.x += wl * hl.x; alo.y += wl * hl.y; alo.z += wl * hl.z; alo.w += wl * hl.w;
      ahi.x += wh * hh.x; ahi.y += wh * hh.y; ahi.z += wh * hh.z; ahi.w += wh * hh.w;
    }
    float il = 1.f / dlo, ih = 1.f / dhi;
    *(float4*)&As[r * 132 +      f * 4] = make_float4(alo.x * il, alo.y * il, alo.z * il, alo.w * il);
    *(float4*)&As[r * 132 + 64 + f * 4] = make_float4(ahi.x * ih, ahi.y * ih, ahi.z * ih, ahi.w * ih);
  }
  __syncthreads();

  // ---- phase B: qkv via split-k outer-product; A broadcast from LDS,
  //      B = coalesced global float4 from inwT[k][col]; no staging ----
  int ln = tid >> 6;                     // node
  int kh = (tid >> 5) & 1;               // k-half
  int tx = tid & 31;                     // col group: cols {p*128 + tx*4..+3}
  float acc[3][4][4] = {};
  {
    const float4* BT = (const float4*)inwT;   // [128][96 f4]
    for (int kg = kh * kgH; kg < (kh + 1) * kgH; ++kg) {  // 16 iters, rolled
      float4 a4[4];
#pragma unroll
      for (int i = 0; i < 4; ++i)             // half-wave-uniform -> broadcast
        a4[i] = *(const float4*)&As[(ln * 4 + i) * 132 + kg * 4];
      float4 bb[12];
#pragma unroll
      for (int kk = 0; kk < 4; ++kk)
#pragma unroll
        for (int p = 0; p < 3; ++p)           // coalesced: lane tx consecutive
          bb[kk * 3 + p] = BT[(size_t)(kg * 4 + kk) * 96 + p * 32 + tx];
#pragma unroll
      for (int kk = 0; kk < 4; ++kk) {
        float av[4];
#pragma unroll
        for (int i = 0; i < 4; ++i)
          av[i] = kk == 0 ? a4[i].x : kk == 1 ? a4[i].y : kk == 2 ? a4[i].z : a4[i].w;
#pragma unroll
        for (int p = 0; p < 3; ++p) {
          float4 b = bb[kk * 3 + p];
#pragma unroll
          for (int i = 0; i < 4; ++i) {
            acc[p][i][0] += av[i] * b.x;
            acc[p][i][1] += av[i] * b.y;
            acc[p][i][2] += av[i] * b.z;
            acc[p][i][3] += av[i] * b.w;
          }
        }
      }
    }
  }
  // reduce the two k-halves (lane = ...kh*32+tx; xor 32 pairs the halves)
#pragma unroll
  for (int p = 0; p < 3; ++p)
#pragma unroll
    for (int i = 0; i < 4; ++i)
#pragma unroll
      for (int j = 0; j < 4; ++j)
        acc[p][i][j] += __shfl_xor(acc[p][i][j], 32);

  // ---- phase C: +inb, then attention entirely in registers (R14) ----
  // acc[p][v][j] = {q,k,v}[node ln][view v][col tx*4+j]; head = tx>>3.
#pragma unroll
  for (int ni = 0; ni < 3; ++ni) {
    float4 ib = *(const float4*)&inb[ni * 128 + tx * 4];
#pragma unroll
    for (int i = 0; i < 4; ++i) {
      acc[ni][i][0] += ib.x; acc[ni][i][1] += ib.y;
      acc[ni][i][2] += ib.z; acc[ni][i][3] += ib.w;
    }
  }
  float S[4][4];
#pragma unroll
  for (int vq = 0; vq < 4; ++vq)
#pragma unroll
    for (int vk = 0; vk < 4; ++vk)
      S[vq][vk] = acc[0][vq][0] * acc[1][vk][0] + acc[0][vq][1] * acc[1][vk][1]
                + acc[0][vq][2] * acc[1][vk][2] + acc[0][vq][3] * acc[1][vk][3];
#pragma unroll
  for (int vq = 0; vq < 4; ++vq)
#pragma unroll
    for (int vk = 0; vk < 4; ++vk) {
      float s = S[vq][vk];
      s += __shfl_xor(s, 1);
      s += __shfl_xor(s, 2);
      s += __shfl_xor(s, 4);
      S[vq][vk] = s * 0.17677669529663687f;  // 1/sqrt(32)
    }
#pragma unroll
  for (int vq = 0; vq < 4; ++vq) {  // softmax over vk (redundant x16)
    float mx = fmaxf(fmaxf(S[vq][0], S[vq][1]), fmaxf(S[vq][2], S[vq][3]));
    float e0 = __expf(S[vq][0] - mx), e1 = __expf(S[vq][1] - mx);
    float e2 = __expf(S[vq][2] - mx), e3 = __expf(S[vq][3] - mx);
    float inv = 1.f / (e0 + e1 + e2 + e3);
    S[vq][0] = e0 * inv; S[vq][1] = e1 * inv; S[vq][2] = e2 * inv; S[vq][3] = e3 * inv;
  }
  float4 ao_r[4];
#pragma unroll
  for (int vq = 0; vq < 4; ++vq) {
    ao_r[vq] = make_float4(
        S[vq][0] * acc[2][0][0] + S[vq][1] * acc[2][1][0] + S[vq][2] * acc[2][2][0] + S[vq][3] * acc[2][3][0],
        S[vq][0] * acc[2][0][1] + S[vq][1] * acc[2][1][1] + S[vq][2] * acc[2][2][1] + S[vq][3] * acc[2][3][1],
        S[vq][0] * acc[2][0][2] + S[vq][1] * acc[2][1][2] + S[vq][2] * acc[2][2][2] + S[vq][3] * acc[2][3][2],
        S[vq][0] * acc[2][0][3] + S[vq][1] * acc[2][1][3] + S[vq][2] * acc[2][2][3] + S[vq][3] * acc[2][3][3]);
  }
  __syncthreads();  // all As reads (phase B) complete before aoS overlay
  if (kh == 0) {
#pragma unroll
    for (int vq = 0; vq < 4; ++vq)       // plain padded rows; k contiguous
      *(float4*)&aoS[(ln * 4 + vq) * 132 + tx * 4] = ao_r[vq];
  }
  __syncthreads();

  // ---- phase D: out_proj split-k outer-product; aoS broadcast + outwT ----
  float oc[4][4] = {};
  {
    const float4* OT = (const float4*)outwT;  // [128][32 f4]
    for (int kg = kh * kgH; kg < (kh + 1) * kgH; ++kg) {  // 16 iters
      float4 a4[4];
#pragma unroll
      for (int i = 0; i < 4; ++i)
        a4[i] = *(const float4*)&aoS[(ln * 4 + i) * 132 + kg * 4];
      float4 bb[4];
#pragma unroll
      for (int kk = 0; kk < 4; ++kk)          // coalesced
        bb[kk] = OT[(size_t)(kg * 4 + kk) * 32 + tx];
#pragma unroll
      for (int kk = 0; kk < 4; ++kk) {
        float av[4];
#pragma unroll
        for (int i = 0; i < 4; ++i)
          av[i] = kk == 0 ? a4[i].x : kk == 1 ? a4[i].y : kk == 2 ? a4[i].z : a4[i].w;
        float4 b = bb[kk];
#pragma unroll
        for (int i = 0; i < 4; ++i) {
          oc[i][0] += av[i] * b.x;
          oc[i][1] += av[i] * b.y;
          oc[i][2] += av[i] * b.z;
          oc[i][3] += av[i] * b.w;
        }
      }
    }
  }
#pragma unroll
  for (int i = 0; i < 4; ++i)
#pragma unroll
    for (int j = 0; j < 4; ++j)
      oc[i][j] += __shfl_xor(oc[i][j], 32);

  if (kh == 0) {  // epilogue: +outb +bias, remap row (node,v) -> (b*4+v)*NN+n
    int nc = tx * 4;
    float4 ob = make_float4(outb[nc] + bias[nc], outb[nc + 1] + bias[nc + 1],
                            outb[nc + 2] + bias[nc + 2], outb[nc + 3] + bias[nc + 3]);
#pragma unroll
    for (int i = 0; i < 4; ++i) {
      int node = g0n + ln, vv = i;       // rows ln*4+i => node ln, view i
      int bg = node / NN, n = node - bg * NN;
      int om = (bg * 4 + vv) * NN + n;
      *(float4*)&out[(size_t)om * DM + nc] =
          make_float4(oc[i][0] + ob.x, oc[i][1] + ob.y,
                      oc[i][2] + ob.z, oc[i][3] + ob.w);
    }
  }
}

extern "C" void kernel_launch(void* const* d_in, const int* in_sizes, int n_in,
                              void* d_out, int out_size, void* d_ws, size_t ws_size,
                              hipStream_t stream) {
  const float* x    = (const float*)d_in[0];
  const float* W    = (const float*)d_in[1];
  const float* att  = (const float*)d_in[2];
  const float* inw  = (const float*)d_in[3];
  const float* inb  = (const float*)d_in[4];
  const float* outw = (const float*)d_in[5];
  const float* outb = (const float*)d_in[6];
  const float* bias = (const float*)d_in[7];
  const int*   ei   = (const int*)d_in[8];
  float* out = (float*)d_out;

  float* ws = (float*)d_ws;
  float* hbuf  = ws;                       // 2,048,000  (b,v,n)-major h
  float* ssrc  = ws + 12500000;            // 16,000 (rows>=1000 never read)
  float* sdst  = ssrc + 16000;             // 16,000
  int*   cnt   = (int*)(sdst + 16000);     //  4,000
  int*   elist = cnt + 4000;               // 192,000 (4000 x CAP)
  float* inwT  = ws + 12800000;            // 49,152  [128][384]
  float* outwT = ws + 12900000;            // 16,384  [128][128]

  // zero cnt only (score reads are predicated)
  hipMemsetAsync(cnt, 0, 4000 * sizeof(int), stream);

  k1_kernel<<<500 + EB + TB, 256, 0, stream>>>(x, W, att, hbuf, ssrc, sdst,
                                               ei, cnt, elist, inw, outw,
                                               inwT, outwT);
  mega2_kernel<<<NTOT / 8, 512, 0, stream>>>(cnt, elist, ssrc, sdst, hbuf,
                                             inwT, inb, outwT, outb, bias, out);
}

// Round 17
// 138.226 us; speedup vs baseline: 1.1423x; 1.1201x over previous
//
#include <hip/hip_runtime.h>

#define NN 1000
#define HEADS_ 4
#define DM 128
#define EE 64000
#define NTOT 4000
#define ETOT 68000
#define CAP 48     // bucket holds ALL edges per dst: deg ~ Poisson(16)+1, P(>=48) ~ 1e-11
#define EB 34      // edge-builder blocks appended to the h-GEMM dispatch
#define QS 388     // qk row stride (pad +4)

// ---------------------------------------------------------------------------
// 64x64 GEMM tile, K=64: C = A @ Wt^T.  k-group swizzle g = q ^ ((r>>2)&15).
// acc[4][4] only across the staged loop -- proven spill-free (R2/R5, 60 VGPR).
// SCORE: fused GAT score epilogue (rows < 1000 only).
// ---------------------------------------------------------------------------
template <int KK, int SCORE>
__device__ void gemm64(int mi, int ni,
                       const float* __restrict__ A, const float* __restrict__ Wt,
                       float* __restrict__ C, int N,
                       const float* __restrict__ att,
                       float* __restrict__ ssrc, float* __restrict__ sdst) {
  __shared__ float As[64 * 64];
  __shared__ float Bs[64 * 64];
  int tid = threadIdx.x;
  int m0 = mi * 64, n0 = ni * 64;
  int tx = tid & 15, ty = tid >> 4;
  const float4* A4 = (const float4*)A;
  const float4* W4 = (const float4*)Wt;
  float acc[4][4] = {};

  for (int c = 0; c < KK / 64; ++c) {
    __syncthreads();
    {
      int q = tid & 15, r0 = tid >> 4;
#pragma unroll
      for (int p = 0; p < 4; ++p) {  // A: 64 rows
        int r = r0 + p * 16;
        float4 v = A4[(size_t)(m0 + r) * (KK / 4) + c * 16 + q];
        *(float4*)&As[r * 64 + ((q ^ ((r >> 2) & 15)) << 2)] = v;
      }
#pragma unroll
      for (int p = 0; p < 4; ++p) {  // B: 64 rows
        int r = r0 + p * 16;
        float4 v = W4[(size_t)(n0 + r) * (KK / 4) + c * 16 + q];
        *(float4*)&Bs[r * 64 + ((q ^ ((r >> 2) & 15)) << 2)] = v;
      }
    }
    __syncthreads();
#pragma unroll 4
    for (int q = 0; q < 16; ++q) {
      float4 a[4], b[4];
      int sa = (q ^ ty) << 2;
      int sb = (q ^ tx) << 2;
#pragma unroll
      for (int i = 0; i < 4; ++i)
        a[i] = *(const float4*)&As[(ty * 4 + i) * 64 + sa];
#pragma unroll
      for (int j = 0; j < 4; ++j)
        b[j] = *(const float4*)&Bs[(tx * 4 + j) * 64 + sb];
#pragma unroll
      for (int i = 0; i < 4; ++i)
#pragma unroll
        for (int j = 0; j < 4; ++j)
          acc[i][j] += a[i].x * b[j].x + a[i].y * b[j].y
                     + a[i].z * b[j].z + a[i].w * b[j].w;
    }
  }

  int nc = n0 + tx * 4;
#pragma unroll
  for (int i = 0; i < 4; ++i) {
    int m = m0 + ty * 4 + i;
    *(float4*)&C[(size_t)m * N + nc] =
        make_float4(acc[i][0], acc[i][1], acc[i][2], acc[i][3]);
  }

  if (SCORE && m0 < NN) {  // uniform per block
    int hsel = tx >> 3;
    int h = ni * 2 + hsel;
    int kb = (tx & 7) * 4;
    float a0[4], a1[4];
#pragma unroll
    for (int j = 0; j < 4; ++j) {
      a0[j] = att[h * 64 + kb + j];
      a1[j] = att[h * 64 + 32 + kb + j];
    }
#pragma unroll
    for (int i = 0; i < 4; ++i) {
      int m = m0 + ty * 4 + i;
      float p0 = 0.f, p1 = 0.f;
#pragma unroll
      for (int j = 0; j < 4; ++j) {
        float g = acc[i][j];
        float lr = g > 0.f ? g : 0.2f * g;
        p0 += a0[j] * lr;
        p1 += a1[j] * lr;
      }
      p0 += __shfl_xor(p0, 1, 16); p1 += __shfl_xor(p1, 1, 16);
      p0 += __shfl_xor(p0, 2, 16); p1 += __shfl_xor(p1, 2, 16);
      p0 += __shfl_xor(p0, 4, 16); p1 += __shfl_xor(p1, 4, 16);
      if ((tx & 7) == 0 && m < NN) {
        ssrc[m * HEADS_ + h] = p0;
        sdst[m * HEADS_ + h] = p1;
      }
    }
  }
}

// -------- K1: blocks 0..499 = h-GEMM (250 m-tiles x 2 n-tiles) + score
//              blocks 500..499+EB = bucket build    (R5 proven)
__global__ __launch_bounds__(256) void k1_kernel(const float* __restrict__ x,
                                                 const float* __restrict__ W,
                                                 const float* __restrict__ att,
                                                 float* __restrict__ hbuf,
                                                 float* __restrict__ ssrc,
                                                 float* __restrict__ sdst,
                                                 const int* __restrict__ ei,
                                                 int* __restrict__ cnt,
                                                 int* __restrict__ elist) {
  int bid = blockIdx.x;
  if (bid < 500) {
    gemm64<64, 1>(bid >> 1, bid & 1, x, W, hbuf, 128, att, ssrc, sdst);
  } else {
    for (int e = (bid - 500) * 256 + threadIdx.x; e < ETOT; e += EB * 256) {
      int s, d;
      if (e < EE) { s = ei[e]; d = ei[EE + e]; }
      else { s = d = e - EE; }  // self loops
      int pos = atomicAdd(&cnt[d], 1);
      if (pos < CAP) elist[d * CAP + pos] = s;
    }
  }
}

// ---------------------------------------------------------------------------
// K2 (mega): gather(16 nodes -> LDS As) + qkv GEMM + MHA + out_proj.
// 250 blocks x 512 threads, 133,120 B dynamic LDS -> 1 block/CU (2 wv/SIMD).
// Session-best verified configuration (R8: 138.1 us total, mega 61 us,
// VGPR 84, FETCH 17 MB, conflicts 448K).  Structure: phases B-D are R2's
// fused3-v2 verbatim; phase A is the R5-proven gather writing As directly.
// LDS: As[64][132] (8448 f, persistent, padded: a-reads 2 rows/wave = free)
//      region2 (24832 f), sequential overlays with barriers:
//        A: exs[16][48][4] (3072) + srcs[16][48] int (768)
//        B: Bs[128][64] at +4096 (qkv weight chunks, R2 swizzle)
//        B-epi..C: qk[64][388]
//        C-epi..D: ao[2][64][64] at +0, Bs2[128][64] at +8192 (dead-qk zone)
// ---------------------------------------------------------------------------
__global__ __launch_bounds__(512) void mega_kernel(const int* __restrict__ cnt,
                                                   const int* __restrict__ elist,
                                                   const float* __restrict__ ssrc,
                                                   const float* __restrict__ sdst,
                                                   const float* __restrict__ hbuf,
                                                   const float* __restrict__ inw,
                                                   const float* __restrict__ inb,
                                                   const float* __restrict__ outw,
                                                   const float* __restrict__ outb,
                                                   const float* __restrict__ bias,
                                                   float* __restrict__ out) {
  extern __shared__ float smem[];
  float* As   = smem;                    // [64][132]
  float* rg2  = smem + 8448;             // region2 base
  float* exsF = rg2;                     // [16][48][4]
  int*   srcsI = (int*)(rg2 + 3072);     // [16][48]
  float* Bs   = rg2 + 4096;              // [128][64] (phase B)
  float* qk   = rg2;                     // [64][QS]  (overlay)
  float* ao   = rg2;                     // [2][64][64] (overlay)
  float* Bs2  = rg2 + 8192;              // [128][64] (phase D overlay)

  int tid = threadIdx.x;
  int g0n = blockIdx.x * 16;             // first node of tile

  // ---- phase A1: stage edges + exp(score per head): 32 threads/node ----
  {
    int ln = tid >> 5, t32 = tid & 31;
    int d = g0n + ln;
    int m = cnt[d]; if (m > CAP) m = CAP;
    for (int base = 0; base < m; base += 8) {
      int i = base + (t32 >> 2);
      if (i < m) {
        int s = elist[d * CAP + i];
        if ((t32 & 3) == 0) srcsI[ln * CAP + i] = s;
        float sc = ssrc[s * HEADS_ + (t32 & 3)] + sdst[d * HEADS_ + (t32 & 3)];
        exsF[ln * 192 + i * 4 + (t32 & 3)] = __expf(sc);  // shift-invariant
      }
    }
  }
  __syncthreads();

  // ---- phase A2: gather-aggregate h rows into As (R5-proven math) ----
  {
    int r = tid >> 3, g = tid & 7;       // row in [0,64), f4-group in [0,8)
    int ln = r >> 2, v = r & 3;
    int d = g0n + ln, b = d / NN;
    int m = cnt[d]; if (m > CAP) m = CAP;
    const float* hbase = hbuf + ((size_t)(b * 4 + v) * NN) * DM + g * 4;
    float4 a0 = make_float4(0.f, 0.f, 0.f, 0.f), a1 = a0, a2 = a0, a3 = a0;
    float4 den = make_float4(1e-16f, 1e-16f, 1e-16f, 1e-16f);
    for (int i = 0; i < m; ++i) {
      float4 ex = *(const float4*)&exsF[ln * 192 + i * 4];
      unsigned sl = (unsigned)(srcsI[ln * CAP + i] - b * NN);
      unsigned sc = sl < NN ? sl : 0u;   // clamped always-valid addr
      const float* hrow = hbase + (size_t)sc * DM;
      float4 h0 = *(const float4*)(hrow);        // head 0 cols g*4..
      float4 h1 = *(const float4*)(hrow + 32);   // head 1
      float4 h2 = *(const float4*)(hrow + 64);   // head 2
      float4 h3 = *(const float4*)(hrow + 96);   // head 3
      den.x += ex.x; den.y += ex.y; den.z += ex.z; den.w += ex.w;
      float w0 = sl < NN ? ex.x : 0.f, w1 = sl < NN ? ex.y : 0.f;
      float w2 = sl < NN ? ex.z : 0.f, w3 = sl < NN ? ex.w : 0.f;
      a0.x += w0 * h0.x; a0.y += w0 * h0.y; a0.z += w0 * h0.z; a0.w += w0 * h0.w;
      a1.x += w1 * h1.x; a1.y += w1 * h1.y; a1.z += w1 * h1.z; a1.w += w1 * h1.w;
      a2.x += w2 * h2.x; a2.y += w2 * h2.y; a2.z += w2 * h2.z; a2.w += w2 * h2.w;
      a3.x += w3 * h3.x; a3.y += w3 * h3.y; a3.z += w3 * h3.z; a3.w += w3 * h3.w;
    }
    float i0 = 1.f / den.x, i1 = 1.f / den.y, i2 = 1.f / den.z, i3 = 1.f / den.w;
    *(float4*)&As[r * 132 +       g * 4] = make_float4(a0.x * i0, a0.y * i0, a0.z * i0, a0.w * i0);
    *(float4*)&As[r * 132 +  32 + g * 4] = make_float4(a1.x * i1, a1.y * i1, a1.z * i1, a1.w * i1);
    *(float4*)&As[r * 132 +  64 + g * 4] = make_float4(a2.x * i2, a2.y * i2, a2.z * i2, a2.w * i2);
    *(float4*)&As[r * 132 +  96 + g * 4] = make_float4(a3.x * i3, a3.y * i3, a3.z * i3, a3.w * i3);
  }

  // ---- phase B: qkv GEMM (fused3-v2 verbatim; A from resident padded As) --
  int tx = tid & 31, ty = tid >> 5;
  float acc[3][4][4] = {};
  {
    const float4* W4 = (const float4*)inw;   // [384][32]
#pragma unroll
    for (int c = 0; c < 2; ++c) {
#pragma unroll
      for (int ni = 0; ni < 3; ++ni) {
        __syncthreads();
        {
          int q = tid & 15, r0 = tid >> 4;   // r0 in [0,32)
#pragma unroll
          for (int p = 0; p < 4; ++p) {      // Bs: 128 weight rows
            int r = r0 + p * 32;
            float4 v = W4[(size_t)(ni * 128 + r) * 32 + c * 16 + q];
            *(float4*)&Bs[r * 64 + ((q ^ ((r >> 2) & 15)) << 2)] = v;
          }
        }
        __syncthreads();
#pragma unroll 4
        for (int q = 0; q < 16; ++q) {
          float4 a[4], b[4];
          int sb = (q ^ (tx & 15)) << 2;
#pragma unroll
          for (int i = 0; i < 4; ++i)
            a[i] = *(const float4*)&As[(ty * 4 + i) * 132 + c * 64 + q * 4];
#pragma unroll
          for (int j = 0; j < 4; ++j)
            b[j] = *(const float4*)&Bs[(tx * 4 + j) * 64 + sb];
#pragma unroll
          for (int i = 0; i < 4; ++i)
#pragma unroll
            for (int j = 0; j < 4; ++j)
              acc[ni][i][j] += a[i].x * b[j].x + a[i].y * b[j].y
                             + a[i].z * b[j].z + a[i].w * b[j].w;
        }
      }
    }
  }
  __syncthreads();  // Bs reads done before qk overlay

  // ---- qk epilogue: +inb, write qk rows ----
#pragma unroll
  for (int ni = 0; ni < 3; ++ni) {
    int nc = ni * 128 + tx * 4;
    float4 bb = *(const float4*)&inb[nc];
#pragma unroll
    for (int i = 0; i < 4; ++i) {
      int r = ty * 4 + i;
      *(float4*)&qk[r * QS + nc] =
          make_float4(acc[ni][i][0] + bb.x, acc[ni][i][1] + bb.y,
                      acc[ni][i][2] + bb.z, acc[ni][i][3] + bb.w);
    }
  }
  __syncthreads();

  // ---- phase C: attention (fused3-v2 verbatim) ----
  int ln = tid >> 5;                     // node within tile (== ty)
  int vq2 = (tid >> 3) & 3, h2 = (tid >> 1) & 3, s2 = tid & 1;
  float aww[4];
  {
    const float* qr = &qk[(ln * 4 + vq2) * QS + h2 * 32 + s2 * 16];
    float4 qv[4];
#pragma unroll
    for (int u = 0; u < 4; ++u) qv[u] = *(const float4*)&qr[u * 4];
    float sc[4];
#pragma unroll
    for (int vk = 0; vk < 4; ++vk) {
      const float* kr = &qk[(ln * 4 + vk) * QS + 128 + h2 * 32 + s2 * 16];
      float s = 0.f;
#pragma unroll
      for (int u = 0; u < 4; ++u) {
        float4 kv = *(const float4*)&kr[u * 4];
        s += qv[u].x * kv.x + qv[u].y * kv.y + qv[u].z * kv.z + qv[u].w * kv.w;
      }
      sc[vk] = s;
    }
#pragma unroll
    for (int vk = 0; vk < 4; ++vk)
      sc[vk] = (sc[vk] + __shfl_xor(sc[vk], 1)) * 0.17677669529663687f;
    float mx = fmaxf(fmaxf(sc[0], sc[1]), fmaxf(sc[2], sc[3]));
    float e0 = __expf(sc[0] - mx), e1 = __expf(sc[1] - mx);
    float e2 = __expf(sc[2] - mx), e3 = __expf(sc[3] - mx);
    float inv = 1.f / (e0 + e1 + e2 + e3);
    aww[0] = e0 * inv; aww[1] = e1 * inv; aww[2] = e2 * inv; aww[3] = e3 * inv;
  }

  // ---- ao = aw @ v: read ALL v first, barrier, then overlay-write ----
  float4 o[4];
#pragma unroll
  for (int u = 0; u < 4; ++u) o[u] = make_float4(0.f, 0.f, 0.f, 0.f);
#pragma unroll
  for (int vk = 0; vk < 4; ++vk) {
    const float* vr = &qk[(ln * 4 + vk) * QS + 256 + h2 * 32 + s2 * 16];
    float w = aww[vk];
#pragma unroll
    for (int u = 0; u < 4; ++u) {
      float4 vv = *(const float4*)&vr[u * 4];
      o[u].x += w * vv.x; o[u].y += w * vv.y;
      o[u].z += w * vv.z; o[u].w += w * vv.w;
    }
  }
  __syncthreads();  // all v reads complete before q/k region overwritten
  {
    int r = ln * 4 + vq2;
#pragma unroll
    for (int u = 0; u < 4; ++u) {
      int qp = h2 * 8 + s2 * 4 + u;      // col f4-group in [0,32)
      int cc = qp >> 4, qg = qp & 15;
      *(float4*)&ao[cc * 4096 + r * 64 + ((qg ^ (ln & 15)) << 2)] = o[u];
    }
  }
  __syncthreads();

  // ---- phase D: out_proj 64x128, K=128 (2 chunks via Bs2); remap write ----
  float oc[4][4] = {};
  const float4* O4 = (const float4*)outw;  // [128][32]
#pragma unroll
  for (int c = 0; c < 2; ++c) {
    {
      int q = tid & 15, r0 = tid >> 4;
#pragma unroll
      for (int p = 0; p < 4; ++p) {       // Bs2: 128 outw rows
        int r = r0 + p * 32;
        float4 v = O4[(size_t)r * 32 + c * 16 + q];
        *(float4*)&Bs2[r * 64 + ((q ^ ((r >> 2) & 15)) << 2)] = v;
      }
    }
    __syncthreads();
#pragma unroll 4
    for (int q = 0; q < 16; ++q) {
      float4 a[4], bq[4];
      int sa = (q ^ ty) << 2;
      int sb = (q ^ (tx & 15)) << 2;
#pragma unroll
      for (int i = 0; i < 4; ++i)
        a[i] = *(const float4*)&ao[c * 4096 + (ty * 4 + i) * 64 + sa];
#pragma unroll
      for (int j = 0; j < 4; ++j)
        bq[j] = *(const float4*)&Bs2[(tx * 4 + j) * 64 + sb];
#pragma unroll
      for (int i = 0; i < 4; ++i)
#pragma unroll
        for (int j = 0; j < 4; ++j)
          oc[i][j] += a[i].x * bq[j].x + a[i].y * bq[j].y
                    + a[i].z * bq[j].z + a[i].w * bq[j].w;
    }
    __syncthreads();
  }

  {  // epilogue: +outb +bias, remap row (node,v) -> (b*4+v)*NN + n
    int nc = tx * 4;
    float4 ob = make_float4(outb[nc] + bias[nc], outb[nc + 1] + bias[nc + 1],
                            outb[nc + 2] + bias[nc + 2], outb[nc + 3] + bias[nc + 3]);
#pragma unroll
    for (int i = 0; i < 4; ++i) {
      int r = ty * 4 + i;
      int node = g0n + (r >> 2), vv = r & 3;
      int bg = node / NN, n = node - bg * NN;
      int om = (bg * 4 + vv) * NN + n;
      *(float4*)&out[(size_t)om * DM + nc] =
          make_float4(oc[i][0] + ob.x, oc[i][1] + ob.y,
                      oc[i][2] + ob.z, oc[i][3] + ob.w);
    }
  }
}

extern "C" void kernel_launch(void* const* d_in, const int* in_sizes, int n_in,
                              void* d_out, int out_size, void* d_ws, size_t ws_size,
                              hipStream_t stream) {
  const float* x    = (const float*)d_in[0];
  const float* W    = (const float*)d_in[1];
  const float* att  = (const float*)d_in[2];
  const float* inw  = (const float*)d_in[3];
  const float* inb  = (const float*)d_in[4];
  const float* outw = (const float*)d_in[5];
  const float* outb = (const float*)d_in[6];
  const float* bias = (const float*)d_in[7];
  const int*   ei   = (const int*)d_in[8];
  float* out = (float*)d_out;

  float* ws = (float*)d_ws;
  float* hbuf  = ws;                       // 2,048,000  (b,v,n)-major h
  float* ssrc  = ws + 12500000;            // 16,000 } contiguous:
  float* sdst  = ssrc + 16000;             // 16,000 } one 144 KB memset
  int*   cnt   = (int*)(sdst + 16000);     //  4,000 }
  int*   elist = cnt + 4000;               // 192,000 (4000 x CAP)

  static int lds_opt_in = 0;
  if (!lds_opt_in) {
    hipFuncSetAttribute((const void*)mega_kernel,
                        hipFuncAttributeMaxDynamicSharedMemorySize, 160 * 1024);
    lds_opt_in = 1;
  }

  // zero ssrc/sdst (rows >=1000 must stay zero) + cnt
  hipMemsetAsync(ssrc, 0, 36000 * sizeof(float), stream);

  k1_kernel<<<500 + EB, 256, 0, stream>>>(x, W, att, hbuf, ssrc, sdst, ei, cnt, elist);
  mega_kernel<<<250, 512, 133120, stream>>>(cnt, elist, ssrc, sdst, hbuf,
                                            inw, inb, outw, outb, bias, out);
}